// Round 13
// baseline (238.312 us; speedup 1.0000x reference)
//
#include <hip/hip_runtime.h>
#include <math.h>

// ---------- types ----------
typedef __attribute__((ext_vector_type(8))) __bf16 bf16x8;
typedef __attribute__((ext_vector_type(4))) float  f32x4;
typedef unsigned short ushort_t;
typedef unsigned int   uint_t;

static __device__ inline f32x4 mfma16(bf16x8 a, bf16x8 b, f32x4 c) {
    return __builtin_amdgcn_mfma_f32_16x16x32_bf16(a, b, c, 0, 0, 0);
}

static __device__ inline ushort_t f2b(float f) {
    uint_t u = __builtin_bit_cast(uint_t, f);
    u = (u + 0x7FFFu + ((u >> 16) & 1u)) >> 16;
    return (ushort_t)u;
}
static __device__ inline float b2f(ushort_t u) {
    uint_t x = ((uint_t)u) << 16;
    return __builtin_bit_cast(float, x);
}
static __device__ inline bf16x8 ld8(const ushort_t* p) {
    uint4 v = *(const uint4*)p;
    return __builtin_bit_cast(bf16x8, v);
}
static __device__ inline float fexp2(float x) {
#if __has_builtin(__builtin_amdgcn_exp2f)
    return __builtin_amdgcn_exp2f(x);
#else
    return exp2f(x);
#endif
}

// async global->LDS, 16B per lane; LDS dst = base + lane*16 (wave-uniform base!)
static __device__ inline void gl_lds16(const ushort_t* g, ushort_t* l) {
    __builtin_amdgcn_global_load_lds(
        (const __attribute__((address_space(1))) void*)(g),
        (__attribute__((address_space(3))) void*)(l),
        16, 0, 0);
}

// ---------- ws layout ----------
// R16: single QKV slab (full-K gemm, no split-K partials).
#define WS_XB     0          //  8 MiB x bf16           [2048,2048]   (dead after QKV gemm)
#define WS_WQKV   8388608    // 12 MiB [Wq;Wk;Wv] bf16  [3072,2048]   (dead after QKV gemm)
#define WS_WO     20971520   //  8 MiB Wo bf16          [2048,2048]
#define WS_P0     29360128   // 12 MiB QKV out bf16     [2048,3072]   (dead after fuse)
#define WS_QBB    0          //  8 MiB q roped bf16     (overlays xb)
#define WS_KBB    8388608    //  2 MiB k roped bf16     (overlays wqkvb head)
#define WS_VTG    10485760   //  2 MiB V^T bf16 [512,2048]
#define WS_AB     12582912   //  8 MiB attn out bf16    (ends exactly at WS_WO)

// ---------- fp32 -> bf16 convert for x|Wq|Wk|Wv|Wo (contiguous dst) ----------
__global__ __launch_bounds__(256) void cvt_all(const float* __restrict__ x,
                                               const float* __restrict__ wq,
                                               const float* __restrict__ wk,
                                               const float* __restrict__ wv,
                                               const float* __restrict__ wo,
                                               ushort_t* __restrict__ dst) {
    const size_t i = (size_t)(blockIdx.x * 256 + threadIdx.x) * 4;
    const float* src; size_t off;
    if (i < 4194304)       { src = x;  off = 0; }
    else if (i < 8388608)  { src = wq; off = 4194304; }
    else if (i < 9437184)  { src = wk; off = 8388608; }
    else if (i < 10485760) { src = wv; off = 9437184; }
    else                   { src = wo; off = 10485760; }
    float4 v = *(const float4*)(src + (i - off));
    ushort4 o;
    o.x = f2b(v.x); o.y = f2b(v.y); o.z = f2b(v.z); o.w = f2b(v.w);
    *(ushort4*)(dst + i) = o;
}

// ---------- 256x128 8-phase GEMM, FULL-K, bf16 out (QKV; R16) ----------
// gemm_op structure (proven R9/R11) with kbeg=0, NT=K/64=32, single bf16 out.
// Grid (24,8) = 192 blocks = same count as the old split-K=2 256^2 QKV ->
// the full-K fusion is occupancy-free this time (R2's failure was occupancy).
// Saves: p1 slab write (12MB) + half of fuse's reads (24MB).
__global__ __launch_bounds__(512, 2) void gemm_fk(const ushort_t* __restrict__ A,
                                                  const ushort_t* __restrict__ Bt,
                                                  ushort_t* __restrict__ Cout,
                                                  int N, int K) {
    __shared__ ushort_t lds[49152];   // 96 KiB
    const int tid  = threadIdx.x;
    const int lane = tid & 63, w = tid >> 6;
    const int qn = lane & 15, quad = lane >> 4;
    const long m0 = (long)blockIdx.y * 256;
    const long n0 = (long)blockIdx.x * 128;
    const int NT = K >> 6;                    // 32: even, >=4
    ushort_t* ldsp = lds;

    const int srow = w * 8 + (lane >> 3);
    const int scol = ((lane & 7) ^ (lane >> 3)) * 8;
    const ushort_t* gA = A + (m0 + srow) * (size_t)K + scol;
    const int srB  = tid >> 3;
    const int scB  = ((tid & 7) ^ (srB & 7)) * 8;
    const ushort_t* gB = Bt + (n0 + srB) * (size_t)K + scB;

    const int wm = w >> 1, wn = w & 1;
    const int aRow = (wm * 32 + qn) * 64;
    const int bRow = (wn * 32 + qn) * 64;
    const int sw0 = ((quad * 16)      ^ ((qn & 7) << 4)) >> 1;
    const int sw1 = ((64 + quad * 16) ^ ((qn & 7) << 4)) >> 1;

#define KSTG_A(t, h, buf)                                                      \
    do { if ((t) < NT) {                                                       \
        const ushort_t* g = gA + (size_t)(h) * 128 * K + (t) * 64;             \
        ushort_t* d = ldsp + (buf) * 24576 + (h) * 8192 + w * 512;             \
        gl_lds16(g, d);                                                        \
        gl_lds16(g + 64 * (size_t)K, d + 4096);                                \
    } } while (0)
#define KSTG_B(t, h, buf)                                                      \
    do { if ((t) < NT) {                                                       \
        const ushort_t* g = gB + (size_t)(h) * 64 * K + (t) * 64;              \
        ushort_t* d = ldsp + (buf) * 24576 + 16384 + (h) * 4096 + w * 512;     \
        gl_lds16(g, d);                                                        \
    } } while (0)

#define KPHASE(cb, p, qr, qc, STAGE, BOUND)                                    \
    do {                                                                       \
        const ushort_t* bA = ldsp + (cb) * 24576 + (qr) * 8192;                \
        const ushort_t* bB = ldsp + (cb) * 24576 + 16384 + (qc) * 4096;        \
        bf16x8 af[2][2], bv[2][2];                                             \
        _Pragma("unroll")                                                      \
        for (int mi = 0; mi < 2; mi++) {                                       \
            af[mi][0] = *(const bf16x8*)(bA + aRow + mi * 1024 + sw0);         \
            af[mi][1] = *(const bf16x8*)(bA + aRow + mi * 1024 + sw1);         \
        }                                                                      \
        _Pragma("unroll")                                                      \
        for (int nj = 0; nj < 2; nj++) {                                       \
            bv[nj][0] = *(const bf16x8*)(bB + bRow + nj * 1024 + sw0);         \
            bv[nj][1] = *(const bf16x8*)(bB + bRow + nj * 1024 + sw1);         \
        }                                                                      \
        asm volatile("" ::: "memory");                                         \
        STAGE;                                                                 \
        BOUND;                                                                 \
        __builtin_amdgcn_s_barrier();                                          \
        asm volatile("s_waitcnt lgkmcnt(0)" ::: "memory");                     \
        __builtin_amdgcn_sched_barrier(0);                                     \
        __builtin_amdgcn_s_setprio(1);                                         \
        _Pragma("unroll")                                                      \
        for (int mi = 0; mi < 2; mi++)                                         \
            _Pragma("unroll")                                                  \
            for (int nj = 0; nj < 2; nj++) {                                   \
                acc[p][mi][nj] = mfma16(af[mi][0], bv[nj][0], acc[p][mi][nj]); \
                acc[p][mi][nj] = mfma16(af[mi][1], bv[nj][1], acc[p][mi][nj]); \
            }                                                                  \
        __builtin_amdgcn_s_setprio(0);                                         \
        __builtin_amdgcn_s_barrier();                                          \
    } while (0)

    f32x4 acc[4][2][2];
    f32x4 zero = {0.f, 0.f, 0.f, 0.f};
    #pragma unroll
    for (int p = 0; p < 4; p++)
        #pragma unroll
        for (int mi = 0; mi < 2; mi++)
            #pragma unroll
            for (int nj = 0; nj < 2; nj++) acc[p][mi][nj] = zero;

    KSTG_A(0, 0, 0); KSTG_B(0, 0, 0); KSTG_B(0, 1, 0); KSTG_A(0, 1, 0);
    KSTG_A(1, 0, 1); KSTG_B(1, 0, 1);
    asm volatile("s_waitcnt vmcnt(0)" ::: "memory");
    __builtin_amdgcn_s_barrier();

    for (int t2 = 0; t2 < NT; t2 += 2) {
        KPHASE(0, 0, 0, 0, KSTG_B(t2 + 1, 1, 1), (void)0);
        KPHASE(0, 1, 0, 1, KSTG_A(t2 + 1, 1, 1), (void)0);
        KPHASE(0, 2, 1, 0, KSTG_A(t2 + 2, 0, 0), (void)0);
        KPHASE(0, 3, 1, 1, KSTG_B(t2 + 2, 0, 0),
               if (t2 == NT - 2) { asm volatile("s_waitcnt vmcnt(0)" ::: "memory"); }
               else              { asm volatile("s_waitcnt vmcnt(3)" ::: "memory"); });
        KPHASE(1, 0, 0, 0, KSTG_B(t2 + 2, 1, 0), (void)0);
        KPHASE(1, 1, 0, 1, KSTG_A(t2 + 2, 1, 0), (void)0);
        KPHASE(1, 2, 1, 0, KSTG_A(t2 + 3, 0, 1), (void)0);
        KPHASE(1, 3, 1, 1, KSTG_B(t2 + 3, 0, 1),
               asm volatile("s_waitcnt vmcnt(3)" ::: "memory"););
    }
#undef KPHASE
#undef KSTG_A
#undef KSTG_B

    #pragma unroll
    for (int p = 0; p < 4; p++) {
        const int qr = p >> 1, qc = p & 1;
        #pragma unroll
        for (int mi = 0; mi < 2; mi++)
            #pragma unroll
            for (int nj = 0; nj < 2; nj++) {
                const long row0 = m0 + qr * 128 + wm * 32 + mi * 16 + quad * 4;
                const long col  = n0 + qc * 64 + wn * 32 + nj * 16 + qn;
                #pragma unroll
                for (int r = 0; r < 4; r++)
                    Cout[(row0 + r) * N + col] = f2b(acc[p][mi][nj][r]);
            }
    }
}

// ---------- 256x64 full-K GEMM, direct fp32 out (O-projection; proven R11) ----------
__global__ __launch_bounds__(512, 2) void gemm_on(const ushort_t* __restrict__ A,
                                                  const ushort_t* __restrict__ Bt,
                                                  float* __restrict__ Cout,
                                                  int N, int K) {
    __shared__ ushort_t lds[40960];   // 80 KiB
    const int tid  = threadIdx.x;
    const int lane = tid & 63, w = tid >> 6;
    const int qn = lane & 15, quad = lane >> 4;
    const long m0 = (long)blockIdx.y * 256;
    const long n0 = (long)blockIdx.x * 64;
    const int NT = K >> 6;                    // 32
    ushort_t* ldsp = lds;

    const int srow = w * 8 + (lane >> 3);
    const int scol = ((lane & 7) ^ (lane >> 3)) * 8;
    const ushort_t* gA = A + (m0 + srow) * (size_t)K + scol;
    const int srB  = tid >> 3;
    const int scB  = ((tid & 7) ^ (srB & 7)) * 8;
    const ushort_t* gB = Bt + (n0 + srB) * (size_t)K + scB;

    const int wm = w >> 1, wn = w & 1;
    const int aRow = (wm * 32 + qn) * 64;
    const int bRow = (wn * 32 + qn) * 64;
    const int sw0 = ((quad * 16)      ^ ((qn & 7) << 4)) >> 1;
    const int sw1 = ((64 + quad * 16) ^ ((qn & 7) << 4)) >> 1;

#define NSTG_A(t, h, buf)                                                      \
    do { if ((t) < NT) {                                                       \
        const ushort_t* g = gA + (size_t)(h) * 128 * K + (t) * 64;             \
        ushort_t* d = ldsp + (buf) * 20480 + (h) * 8192 + w * 512;             \
        gl_lds16(g, d);                                                        \
        gl_lds16(g + 64 * (size_t)K, d + 4096);                                \
    } } while (0)
#define NSTG_B(t, buf)                                                         \
    do { if ((t) < NT) {                                                       \
        const ushort_t* g = gB + (size_t)(t) * 64;                             \
        ushort_t* d = ldsp + (buf) * 20480 + 16384 + w * 512;                  \
        gl_lds16(g, d);                                                        \
    } } while (0)

#define NPHASE(cb, qr, STAGE, BOUND)                                           \
    do {                                                                       \
        const ushort_t* bA = ldsp + (cb) * 20480 + (qr) * 8192;                \
        const ushort_t* bB = ldsp + (cb) * 20480 + 16384;                      \
        bf16x8 af[2][2], bv[2][2];                                             \
        _Pragma("unroll")                                                      \
        for (int mi = 0; mi < 2; mi++) {                                       \
            af[mi][0] = *(const bf16x8*)(bA + aRow + mi * 1024 + sw0);         \
            af[mi][1] = *(const bf16x8*)(bA + aRow + mi * 1024 + sw1);         \
        }                                                                      \
        _Pragma("unroll")                                                      \
        for (int nj = 0; nj < 2; nj++) {                                       \
            bv[nj][0] = *(const bf16x8*)(bB + bRow + nj * 1024 + sw0);         \
            bv[nj][1] = *(const bf16x8*)(bB + bRow + nj * 1024 + sw1);         \
        }                                                                      \
        asm volatile("" ::: "memory");                                         \
        STAGE;                                                                 \
        BOUND;                                                                 \
        __builtin_amdgcn_s_barrier();                                          \
        asm volatile("s_waitcnt lgkmcnt(0)" ::: "memory");                     \
        __builtin_amdgcn_sched_barrier(0);                                     \
        __builtin_amdgcn_s_setprio(1);                                         \
        _Pragma("unroll")                                                      \
        for (int mi = 0; mi < 2; mi++)                                         \
            _Pragma("unroll")                                                  \
            for (int nj = 0; nj < 2; nj++) {                                   \
                acc[qr][mi][nj] = mfma16(af[mi][0], bv[nj][0], acc[qr][mi][nj]); \
                acc[qr][mi][nj] = mfma16(af[mi][1], bv[nj][1], acc[qr][mi][nj]); \
            }                                                                  \
        __builtin_amdgcn_s_setprio(0);                                         \
        __builtin_amdgcn_s_barrier();                                          \
    } while (0)

    f32x4 acc[2][2][2];
    f32x4 zero = {0.f, 0.f, 0.f, 0.f};
    #pragma unroll
    for (int p = 0; p < 2; p++)
        #pragma unroll
        for (int mi = 0; mi < 2; mi++)
            #pragma unroll
            for (int nj = 0; nj < 2; nj++) acc[p][mi][nj] = zero;

    NSTG_A(0, 0, 0); NSTG_A(0, 1, 0); NSTG_B(0, 0);
    NSTG_A(1, 0, 1);
    asm volatile("s_waitcnt vmcnt(0)" ::: "memory");
    __builtin_amdgcn_s_barrier();

    for (int t = 0; t < NT; t++) {
        const int cb = t & 1;
        NPHASE(cb, 0, { NSTG_A(t + 1, 1, cb ^ 1); NSTG_B(t + 1, cb ^ 1); },
               (void)0);
        NPHASE(cb, 1, { NSTG_A(t + 2, 0, cb); },
               if (t == NT - 2) { asm volatile("s_waitcnt vmcnt(0)" ::: "memory"); }
               else             { asm volatile("s_waitcnt vmcnt(2)" ::: "memory"); });
    }
#undef NPHASE
#undef NSTG_A
#undef NSTG_B

    #pragma unroll
    for (int p = 0; p < 2; p++)
        #pragma unroll
        for (int mi = 0; mi < 2; mi++)
            #pragma unroll
            for (int nj = 0; nj < 2; nj++) {
                const long row0 = m0 + p * 128 + wm * 32 + mi * 16 + quad * 4;
                const long col  = n0 + wn * 32 + nj * 16 + qn;
                #pragma unroll
                for (int r = 0; r < 4; r++)
                    Cout[(row0 + r) * N + col] = acc[p][mi][nj][r];
            }
}

// ---------- fused RoPE + V-transpose, single slab (R16) ----------
__global__ __launch_bounds__(256) void fuse_crv(const ushort_t* __restrict__ p0,
                                                const float* __restrict__ cs,
                                                const float* __restrict__ sn,
                                                ushort_t* __restrict__ qd,
                                                ushort_t* __restrict__ kd,
                                                ushort_t* __restrict__ vt) {
    __shared__ ushort_t tl[64][65];
    const int cx = blockIdx.x;               // 0..47
    const int ty = blockIdx.y;               // 0..31
    const int r  = threadIdx.x >> 2;         // 0..63
    const int c0 = (threadIdx.x & 3) << 4;   // 0,16,32,48
    const int t  = ty * 64 + r;
    const size_t base = (size_t)t * 3072 + cx * 64;

    if (cx < 40) {                           // q or k: rope
        const int cp = c0 ^ 32;
        float own[16], par[16];
        #pragma unroll
        for (int jj = 0; jj < 2; jj++) {
            uint4 a = *(const uint4*)(p0 + base + c0 + jj * 8);
            uint4 c = *(const uint4*)(p0 + base + cp + jj * 8);
            const ushort_t* pa = (const ushort_t*)&a;
            const ushort_t* pc = (const ushort_t*)&c;
            #pragma unroll
            for (int e = 0; e < 8; e++) {
                own[jj * 8 + e] = b2f(pa[e]);
                par[jj * 8 + e] = b2f(pc[e]);
            }
        }
        float cs16[16], sn16[16];
        #pragma unroll
        for (int jj = 0; jj < 4; jj++) {
            float4 c4 = *(const float4*)(cs + (size_t)t * 64 + c0 + jj * 4);
            float4 s4 = *(const float4*)(sn + (size_t)t * 64 + c0 + jj * 4);
            cs16[jj * 4 + 0] = c4.x; cs16[jj * 4 + 1] = c4.y;
            cs16[jj * 4 + 2] = c4.z; cs16[jj * 4 + 3] = c4.w;
            sn16[jj * 4 + 0] = s4.x; sn16[jj * 4 + 1] = s4.y;
            sn16[jj * 4 + 2] = s4.z; sn16[jj * 4 + 3] = s4.w;
        }
        const float scale = (cx < 32) ? 0.18033688f : 1.0f;  // q: (1/8)*log2e
        union { ushort_t u[16]; uint4 v[2]; } o;
        #pragma unroll
        for (int j = 0; j < 16; j++) {
            const int d = c0 + j;
            const float pr = (d < 32) ? -par[j] : par[j];
            o.u[j] = f2b((own[j] * cs16[j] + pr * sn16[j]) * scale);
        }
        if (cx < 32) {
            ushort_t* dst = qd + (size_t)t * 2048 + cx * 64 + c0;
            *(uint4*)dst = o.v[0]; *(uint4*)(dst + 8) = o.v[1];
        } else {
            ushort_t* dst = kd + (size_t)t * 512 + (cx - 32) * 64 + c0;
            *(uint4*)dst = o.v[0]; *(uint4*)(dst + 8) = o.v[1];
        }
    } else {                                 // v: transpose via LDS
        #pragma unroll
        for (int jj = 0; jj < 2; jj++) {
            uint4 a = *(const uint4*)(p0 + base + c0 + jj * 8);
            const ushort_t* pa = (const ushort_t*)&a;
            #pragma unroll
            for (int e = 0; e < 8; e++)
                tl[r][c0 + jj * 8 + e] = pa[e];
        }
        __syncthreads();
        const int rr  = threadIdx.x >> 3;        // 0..31
        const int cc8 = (threadIdx.x & 7) * 8;
        const int db = (cx - 40) * 64, tb = ty * 64;
        #pragma unroll
        for (int h = 0; h < 2; h++) {
            const int d = rr + h * 32;
            ushort4 o0, o1;
            o0.x = tl[cc8 + 0][d]; o0.y = tl[cc8 + 1][d];
            o0.z = tl[cc8 + 2][d]; o0.w = tl[cc8 + 3][d];
            o1.x = tl[cc8 + 4][d]; o1.y = tl[cc8 + 5][d];
            o1.z = tl[cc8 + 6][d]; o1.w = tl[cc8 + 7][d];
            *(ushort4*)(vt + (size_t)(db + d) * 2048 + tb + cc8)     = o0;
            *(ushort4*)(vt + (size_t)(db + d) * 2048 + tb + cc8 + 4) = o1;
        }
    }
}

// ---------- flash attention, causal, GQA G=4 (R12 verbatim: swapped QK^T) ----------
__global__ __launch_bounds__(256) void attn_kernel(const ushort_t* __restrict__ Q,
                                                   const ushort_t* __restrict__ Kb,
                                                   const ushort_t* __restrict__ Vt,
                                                   ushort_t* __restrict__ Ob) {
    __shared__ ushort_t Ks[2 * 4096];     // 16 KB
    __shared__ ushort_t Vs[2 * 4096];     // 16 KB
    __shared__ ushort_t pl[4 * 16 * 72];  // 9 KB: per-wave P, 16 rows (stride 72)
    const int tid  = threadIdx.x;
    const int lane = tid & 63, wid = tid >> 6;
    const int qn = lane & 15, quad = lane >> 4;
    const int h   = blockIdx.x & 31;
    const int qb  = 31 - (blockIdx.x >> 5);     // heavy first, 0..31 (64-row blocks)
    const int kvb = (h >> 2) * 64;
    const int trow = qb * 64 + wid * 16;
    ushort_t* plw = pl + wid * 16 * 72;
    f32x4 zero = {0.f, 0.f, 0.f, 0.f};

    const ushort_t* qpA = Q + (size_t)(trow + qn) * 2048 + h * 64 + quad * 8;
    const bf16x8 qA0 = ld8(qpA), qA1 = ld8(qpA + 32);

    f32x4 oA[4] = {zero, zero, zero, zero};
    float lsum = 0.f;
    const int ntiles = qb + 1;

#define STAGE(s0, buf)                                                         \
    do {                                                                       \
        const ushort_t* kg = Kb + (size_t)((s0) + lane) * 512 + kvb + wid * 8; \
        gl_lds16(kg,      Ks + (buf) * 4096 + wid * 512);                      \
        gl_lds16(kg + 32, Ks + (buf) * 4096 + (wid + 4) * 512);                \
        const ushort_t* vg = Vt + (size_t)(kvb + lane) * 2048 + (s0) + wid * 8;\
        gl_lds16(vg,      Vs + (buf) * 4096 + wid * 512);                      \
        gl_lds16(vg + 32, Vs + (buf) * 4096 + (wid + 4) * 512);                \
    } while (0)

#define COMPUTE(s0, buf)                                                       \
    do {                                                                       \
        f32x4 scA[4];                                                          \
        __builtin_amdgcn_s_setprio(1);                                         \
        _Pragma("unroll")                                                      \
        for (int cb = 0; cb < 4; cb++) {                                       \
            const bf16x8 kf0 = *(const bf16x8*)(Ks + (buf) * 4096 + quad * 512 + (cb * 16 + qn) * 8);       \
            const bf16x8 kf1 = *(const bf16x8*)(Ks + (buf) * 4096 + (quad + 4) * 512 + (cb * 16 + qn) * 8); \
            f32x4 s = mfma16(kf0, qA0, zero); scA[cb] = mfma16(kf1, qA1, s);   \
        }                                                                      \
        __builtin_amdgcn_s_setprio(0);                                         \
        const bool needmask = ((s0) + 63 > trow);                              \
        const int tA = trow + qn;                                              \
        _Pragma("unroll")                                                      \
        for (int cb = 0; cb < 4; cb++) {                                       \
            float pv0, pv1, pv2, pv3;                                          \
            {                                                                  \
                const int colb = (s0) + cb * 16 + quad * 4;                    \
                float v0 = scA[cb][0], v1 = scA[cb][1];                        \
                float v2 = scA[cb][2], v3 = scA[cb][3];                        \
                if (needmask) {                                                \
                    if (colb + 0 > tA) v0 = -INFINITY;                         \
                    if (colb + 1 > tA) v1 = -INFINITY;                         \
                    if (colb + 2 > tA) v2 = -INFINITY;                         \
                    if (colb + 3 > tA) v3 = -INFINITY;                         \
                }                                                              \
                pv0 = fexp2(v0); pv1 = fexp2(v1);                              \
                pv2 = fexp2(v2); pv3 = fexp2(v3);                              \
            }                                                                  \
            lsum += pv0 + pv1 + pv2 + pv3;                                     \
            uint_t w0, w1;                                                     \
            asm("v_cvt_pk_bf16_f32 %0, %1, %2" : "=v"(w0) : "v"(pv0), "v"(pv1)); \
            asm("v_cvt_pk_bf16_f32 %0, %1, %2" : "=v"(w1) : "v"(pv2), "v"(pv3)); \
            uint2 pk; pk.x = w0; pk.y = w1;                                    \
            *(uint2*)(plw + qn * 72 + cb * 16 + quad * 4) = pk;                \
        }                                                                      \
        const bf16x8 pfA0 = *(const bf16x8*)(plw + qn * 72 + quad * 8);        \
        const bf16x8 pfA1 = *(const bf16x8*)(plw + qn * 72 + 32 + quad * 8);   \
        __builtin_amdgcn_s_setprio(1);                                         \
        _Pragma("unroll")                                                      \
        for (int dcb = 0; dcb < 4; dcb++) {                                    \
            const bf16x8 vf0 = *(const bf16x8*)(Vs + (buf) * 4096 + quad * 512 + (dcb * 16 + qn) * 8);       \
            const bf16x8 vf1 = *(const bf16x8*)(Vs + (buf) * 4096 + (quad + 4) * 512 + (dcb * 16 + qn) * 8); \
            oA[dcb] = mfma16(pfA0, vf0, oA[dcb]);                              \
            oA[dcb] = mfma16(pfA1, vf1, oA[dcb]);                              \
        }                                                                      \
        __builtin_amdgcn_s_setprio(0);                                         \
    } while (0)

    STAGE(0, 0);
    int t = 0;
    for (; t + 2 <= ntiles; t += 2) {
        __syncthreads();
        STAGE((t + 1) * 64, 1);
        COMPUTE(t * 64, 0);
        __syncthreads();
        if (t + 2 < ntiles) STAGE((t + 2) * 64, 0);
        COMPUTE((t + 1) * 64, 1);
    }
    if (t < ntiles) {                      // odd tail: buf0 already staged
        __syncthreads();
        COMPUTE(t * 64, 0);
    }
#undef STAGE
#undef COMPUTE

    // row-sum: lanes qn, qn+16, qn+32, qn+48 hold partial sums for q-row qn
    float sA = lsum;
    sA += __shfl_xor(sA, 16, 64);
    sA += __shfl_xor(sA, 32, 64);
    #pragma unroll
    for (int i = 0; i < 4; i++) {
        const float invA = 1.0f / __shfl(sA, quad * 4 + i, 64);
        ushort_t* obA = Ob + (size_t)(trow + quad * 4 + i) * 2048 + h * 64 + qn;
        obA[0]  = f2b(oA[0][i] * invA);
        obA[16] = f2b(oA[1][i] * invA);
        obA[32] = f2b(oA[2][i] * invA);
        obA[48] = f2b(oA[3][i] * invA);
    }
}

// ---------- launch ----------
extern "C" void kernel_launch(void* const* d_in, const int* in_sizes, int n_in,
                              void* d_out, int out_size, void* d_ws, size_t ws_size,
                              hipStream_t stream) {
    const float* x    = (const float*)d_in[0];
    const float* cosp = (const float*)d_in[1];
    const float* sinp = (const float*)d_in[2];
    // d_in[3] = attention_mask_4d (pure causal; recomputed in-kernel)
    const float* Wq = (const float*)d_in[4];
    const float* Wk = (const float*)d_in[5];
    const float* Wv = (const float*)d_in[6];
    const float* Wo = (const float*)d_in[7];
    char* ws = (char*)d_ws;
    (void)ws_size; (void)in_sizes; (void)n_in; (void)out_size;

    ushort_t* xb    = (ushort_t*)(ws + WS_XB);
    ushort_t* wqkvb = (ushort_t*)(ws + WS_WQKV);
    ushort_t* wob   = (ushort_t*)(ws + WS_WO);
    ushort_t* p0    = (ushort_t*)(ws + WS_P0);
    ushort_t* qbb   = (ushort_t*)(ws + WS_QBB);
    ushort_t* kbb   = (ushort_t*)(ws + WS_KBB);
    ushort_t* vtg   = (ushort_t*)(ws + WS_VTG);
    ushort_t* ab    = (ushort_t*)(ws + WS_AB);

    // 1. convert inputs/weights to bf16 (contiguous dst: xb|wqkvb|wob)
    cvt_all<<<14336, 256, 0, stream>>>(x, Wq, Wk, Wv, Wo, xb);

    // 2. QKV projection FULL-K 256x128 (gemm_op structure): 192 blocks — same
    //    count as old split-K; single bf16 slab, p1 + combine eliminated.
    gemm_fk<<<dim3(24, 8), 512, 0, stream>>>(xb, wqkvb, p0, 3072, 2048);

    // 3. fused RoPE(q scale=(1/8)*log2e) + V transpose, single slab
    fuse_crv<<<dim3(48, 32), 256, 0, stream>>>(p0, cosp, sinp, qbb, kbb, vtg);

    // 4. attention: 1024 blocks, 64 q-rows each (R12 verbatim)
    attn_kernel<<<1024, 256, 0, stream>>>(qbb, kbb, vtg, ab);

    // 5. O-projection: 256x64 full-K, 256 blocks = 1/CU, direct fp32 out (R11 verbatim)
    gemm_on<<<dim3(32, 8), 512, 0, stream>>>(ab, wob, (float*)d_out, 2048, 2048);
}